// Round 4
// baseline (284.589 us; speedup 1.0000x reference)
//
#include <hip/hip_runtime.h>

// DiceLoss: predict,target fp32 [B=2, O=4, D=64, H=256, W=256]
// out = mean over (b,o) of [ sum_d valid*(1 - 2*num/den) / sum_d valid ]
// num = sum_hw sigmoid(p)*t ; den = sum_hw sigmoid(p) + sum_hw t + 1
// valid = (t[b,o,d,0] != -1)
//
// R4 = R3 structure with the slice-index bug fixed (b>>6, not b>>4).
// Chip-wide ROLLING WINDOW: per step k the whole grid reads one contiguous
// 8 MB window of predict and of target (consecutive blocks -> consecutive
// 1 KB lines -> all HBM channels active, max row locality). R0-R2 proved the
// static mapping (resident blocks scattered stride-64KB over 134 MB) is stuck
// at 2.58 TB/s regardless of per-wave MLP structure.

constexpr int HW        = 256 * 256;       // 65536 floats per slice
constexpr int NSLICE    = 2 * 4 * 64;      // 512 slices
constexpr int NPAIR     = 2 * 4;           // 8 (b,o) pairs
constexpr int THREADS   = 256;
constexpr int NBLK      = 2048;
constexpr int F4_SLICE  = HW / 4;                    // 16384 float4 per slice
constexpr int F4_TOTAL  = NSLICE * F4_SLICE;         // 8,388,608 float4
constexpr int F4_STEP   = NBLK * THREADS;            // 524,288 float4 = 8 MB window
constexpr int KSTEPS    = F4_TOTAL / F4_STEP;        // 16
constexpr int SLICES_PER_STEP = F4_STEP / F4_SLICE;  // 32
constexpr int BLK_PER_SLICE   = F4_SLICE / THREADS;  // 64

typedef float v4 __attribute__((ext_vector_type(4)));

// ws layout (floats): [0..511]=sum(sig*t), [512..1023]=sum(sig), [1024..1535]=sum(t)

__global__ void zero_ws(float* __restrict__ ws)
{
    const int i = blockIdx.x * blockDim.x + threadIdx.x;
    if (i < 3 * NSLICE) ws[i] = 0.f;
}

__global__ __launch_bounds__(THREADS) void dice_stage1(
    const float* __restrict__ predict,
    const float* __restrict__ target,
    float* __restrict__ ws)
{
    const int b    = blockIdx.x;
    const int tid  = threadIdx.x;
    const int wave = tid >> 6;
    const int lane = tid & 63;
    // Per step k, this block's 1024 floats all lie in slice k*32 + (b>>6):
    // block covers float4 [k*F4_STEP + b*256, +256); slice = that / 16384.
    const int slice_base = b / BLK_PER_SLICE;   // b >> 6

    __shared__ float l_pt[2][THREADS / 64];
    __shared__ float l_p [2][THREADS / 64];
    __shared__ float l_t [2][THREADS / 64];

    const v4* __restrict__ p4 = (const v4*)predict;
    const v4* __restrict__ t4 = (const v4*)target;

    for (int k = 0; k < KSTEPS; ++k) {
        const size_t g = (size_t)k * F4_STEP + (size_t)b * THREADS + tid;
        // predict: nontemporal (no LLC alloc) so target can stay L3-resident
        // instead of the two 134 MB streams thrashing the 256 MB L3.
        const v4 pv = __builtin_nontemporal_load(p4 + g);
        const v4 tv = t4[g];

        const float e0 = 1.f / (1.f + __expf(-pv.x));
        const float e1 = 1.f / (1.f + __expf(-pv.y));
        const float e2 = 1.f / (1.f + __expf(-pv.z));
        const float e3 = 1.f / (1.f + __expf(-pv.w));

        float s_pt = e0 * tv.x + e1 * tv.y + e2 * tv.z + e3 * tv.w;
        float s_p  = (e0 + e1) + (e2 + e3);
        float s_t  = (tv.x + tv.y) + (tv.z + tv.w);

#pragma unroll
        for (int off = 32; off > 0; off >>= 1) {
            s_pt += __shfl_down(s_pt, off, 64);
            s_p  += __shfl_down(s_p,  off, 64);
            s_t  += __shfl_down(s_t,  off, 64);
        }
        const int par = k & 1;   // parity double-buffer: tid0 reads buf[par]
        if (lane == 0) {         // while iter k+1 writes buf[par^1]; the k+1
            l_pt[par][wave] = s_pt;  // barrier orders the k+2 overwrite.
            l_p [par][wave] = s_p;
            l_t [par][wave] = s_t;
        }
        __syncthreads();
        if (tid == 0) {
            float pt = 0.f, sp = 0.f, st = 0.f;
#pragma unroll
            for (int w = 0; w < THREADS / 64; ++w) {
                pt += l_pt[par][w]; sp += l_p[par][w]; st += l_t[par][w];
            }
            const int s = k * SLICES_PER_STEP + slice_base;
            atomicAdd(&ws[s],              pt);
            atomicAdd(&ws[NSLICE + s],     sp);
            atomicAdd(&ws[2 * NSLICE + s], st);
        }
    }
}

__global__ __launch_bounds__(NSLICE) void dice_stage2(
    const float* __restrict__ ws,
    const float* __restrict__ target,
    float* __restrict__ out)
{
    const int tid = threadIdx.x;          // 0..511 = slice id; wave w = (b,o) pair
    const float pt = ws[tid];
    const float sp = ws[NSLICE + tid];
    const float st = ws[2 * NSLICE + tid];

    const float valid = (target[(size_t)tid * HW] != -1.0f) ? 1.0f : 0.0f;
    const float den   = sp + st + 1.0f;                 // SMOOTH = 1
    const float dice  = 1.0f - 2.0f * pt / den;

    float dv = dice * valid;
    float v  = valid;
#pragma unroll
    for (int off = 32; off > 0; off >>= 1) {
        dv += __shfl_down(dv, off, 64);
        v  += __shfl_down(v,  off, 64);
    }
    __shared__ float pair_avg[NPAIR];
    const int wave = tid >> 6;
    const int lane = tid & 63;
    if (lane == 0) pair_avg[wave] = dv / v;
    __syncthreads();
    if (tid == 0) {
        float s = 0.f;
#pragma unroll
        for (int w = 0; w < NPAIR; ++w) s += pair_avg[w];
        out[0] = s * (1.0f / NPAIR);
    }
}

extern "C" void kernel_launch(void* const* d_in, const int* in_sizes, int n_in,
                              void* d_out, int out_size, void* d_ws, size_t ws_size,
                              hipStream_t stream) {
    const float* predict = (const float*)d_in[0];
    const float* target  = (const float*)d_in[1];
    float* ws  = (float*)d_ws;
    float* out = (float*)d_out;

    zero_ws<<<3, 512, 0, stream>>>(ws);
    dice_stage1<<<NBLK, THREADS, 0, stream>>>(predict, target, ws);
    dice_stage2<<<1, NSLICE, 0, stream>>>(ws, target, out);
}